// Round 1
// baseline (1842.782 us; speedup 1.0000x reference)
//
#include <hip/hip_runtime.h>
#include <cstdint>
#include <cstddef>

#define TPB 256

namespace {

constexpr int B_SZ = 2;
constexpr int C    = 128;
constexpr int HALF = 64;
constexpr int L    = 4096;   // 64*64
constexpr int N    = 16;
constexpr int HH   = 64;
constexpr int WW   = 64;
constexpr int NC   = 64;     // number of chunks
constexpr int CS   = 64;     // chunk size (NC*CS == L)

__device__ __forceinline__ float softplusf(float x) {
  return fmaxf(x, 0.f) + log1pf(expf(-fabsf(x)));
}
__device__ __forceinline__ float sigm(float x) { return 1.f / (1.f + expf(-x)); }

// ---------- channel-first LayerNorm, one thread per pixel ----------
__global__ void k_ln_cf(const float* __restrict__ X, int bsX,
                        const float* __restrict__ w, const float* __restrict__ bchan,
                        float* __restrict__ Y, int bsY, int Cn, float eps) {
  int p = blockIdx.x * TPB + threadIdx.x;      // p in [0, B*L)
  int b = p / L, l = p % L;
  const float* Xp = X + (size_t)b * bsX + l;
  float s = 0.f, s2 = 0.f;
  for (int c = 0; c < Cn; ++c) { float v = Xp[(size_t)c * L]; s += v; s2 += v * v; }
  float mean = s / Cn;
  float var  = s2 / Cn - mean * mean;
  float rinv = rsqrtf(var + eps);
  float* Yp = Y + (size_t)b * bsY + l;
  for (int c = 0; c < Cn; ++c) {
    float v = Xp[(size_t)c * L];
    Yp[(size_t)c * L] = w[c] * (v - mean) * rinv + bchan[c];
  }
}

// ---------- LN over concat([yf, reverse_L(yb)]) ----------
__global__ void k_ln_cat(const float* __restrict__ yf, const float* __restrict__ ybr,
                         const float* __restrict__ w, const float* __restrict__ bchan,
                         float* __restrict__ Y) {
  int p = blockIdx.x * TPB + threadIdx.x;
  int b = p / L, l = p % L;
  const float* f0 = yf  + (size_t)b * HALF * L + l;
  const float* b0 = ybr + (size_t)b * HALF * L + (L - 1 - l);
  float s = 0.f, s2 = 0.f;
  for (int c = 0; c < HALF; ++c) { float v = f0[(size_t)c * L]; s += v; s2 += v * v; }
  for (int c = 0; c < HALF; ++c) { float v = b0[(size_t)c * L]; s += v; s2 += v * v; }
  float mean = s / C, var = s2 / C - mean * mean;
  float rinv = rsqrtf(var + 1e-6f);
  float* Yp = Y + (size_t)b * C * L + l;
  for (int c = 0; c < HALF; ++c) {
    float v = f0[(size_t)c * L];
    Yp[(size_t)c * L] = w[c] * (v - mean) * rinv + bchan[c];
  }
  for (int c = 0; c < HALF; ++c) {
    float v = b0[(size_t)c * L];
    Yp[(size_t)(HALF + c) * L] = w[HALF + c] * (v - mean) * rinv + bchan[HALF + c];
  }
}

// ---------- 1x1 conv: Y[b,o,l] = sum_i W[o,i]*X[b,i,l] + bias[o] ----------
// grid (L/TPB, O/O_PB, B). EPI: 0 none, 1 sigmoid. BLO: write (B,L,O) layout.
template <int O_PB, int EPI, bool BLO>
__global__ void k_conv1x1(const float* __restrict__ X, int bsX,
                          const float* __restrict__ W, const float* __restrict__ bias,
                          float* __restrict__ Y, int I, int O) {
  __shared__ float Wl[O_PB * 256];
  const int o0 = blockIdx.y * O_PB;
  const int b  = blockIdx.z;
  for (int t = threadIdx.x; t < O_PB * I; t += TPB) {
    int i = t / O_PB, k = t % O_PB;
    Wl[t] = W[(size_t)(o0 + k) * I + i];
  }
  __syncthreads();
  const int l = blockIdx.x * TPB + threadIdx.x;
  const float* Xb = X + (size_t)b * bsX + l;
  float acc[O_PB];
#pragma unroll
  for (int k = 0; k < O_PB; ++k) acc[k] = bias[o0 + k];
#pragma unroll 4
  for (int i = 0; i < I; ++i) {
    float xv = Xb[(size_t)i * L];
#pragma unroll
    for (int k = 0; k < O_PB; ++k) acc[k] += Wl[i * O_PB + k] * xv;
  }
#pragma unroll
  for (int k = 0; k < O_PB; ++k) {
    float v = acc[k];
    if (EPI == 1) v = sigm(v);
    if (BLO) Y[((size_t)b * L + l) * O + o0 + k] = v;
    else     Y[((size_t)b * O + o0 + k) * L + l] = v;
  }
}

// ---------- 1x1 conv over concat of two (B,128,L) tensors ----------
template <int O_PB, int EPI>
__global__ void k_conv1x1_cat2(const float* __restrict__ X1, int bs1,
                               const float* __restrict__ X2, int bs2,
                               const float* __restrict__ W, const float* __restrict__ bias,
                               float* __restrict__ Y, int O) {
  __shared__ float Wl[O_PB * 256];
  const int o0 = blockIdx.y * O_PB;
  const int b  = blockIdx.z;
  for (int t = threadIdx.x; t < O_PB * 256; t += TPB) {
    int i = t / O_PB, k = t % O_PB;
    Wl[t] = W[(size_t)(o0 + k) * 256 + i];
  }
  __syncthreads();
  const int l = blockIdx.x * TPB + threadIdx.x;
  const float* Xb1 = X1 + (size_t)b * bs1 + l;
  const float* Xb2 = X2 + (size_t)b * bs2 + l;
  float acc[O_PB];
#pragma unroll
  for (int k = 0; k < O_PB; ++k) acc[k] = bias[o0 + k];
#pragma unroll 4
  for (int i = 0; i < 128; ++i) {
    float xv = Xb1[(size_t)i * L];
#pragma unroll
    for (int k = 0; k < O_PB; ++k) acc[k] += Wl[i * O_PB + k] * xv;
  }
#pragma unroll 4
  for (int i = 0; i < 128; ++i) {
    float xv = Xb2[(size_t)i * L];
#pragma unroll
    for (int k = 0; k < O_PB; ++k) acc[k] += Wl[(128 + i) * O_PB + k] * xv;
  }
#pragma unroll
  for (int k = 0; k < O_PB; ++k) {
    float v = acc[k];
    if (EPI == 1) v = sigm(v);
    Y[((size_t)b * O + o0 + k) * L + l] = v;
  }
}

// ---------- depthwise 3x3 SAME + bias + SiLU ----------
__global__ void k_dwconv_silu(const float* __restrict__ X, int bsX,
                              const float* __restrict__ W9, const float* __restrict__ bias,
                              float* __restrict__ Y) {
  int c = blockIdx.y, b = blockIdx.z;
  int l = blockIdx.x * TPB + threadIdx.x;
  int h = l / WW, w = l % WW;
  const float* Xc = X + (size_t)b * bsX + (size_t)c * L;
  float acc = bias[c];
#pragma unroll
  for (int kh = 0; kh < 3; ++kh) {
    int hh = h + kh - 1;
    if (hh < 0 || hh >= HH) continue;
#pragma unroll
    for (int kw = 0; kw < 3; ++kw) {
      int ww2 = w + kw - 1;
      if (ww2 < 0 || ww2 >= WW) continue;
      acc += Xc[hh * WW + ww2] * W9[c * 9 + kh * 3 + kw];
    }
  }
  Y[((size_t)b * C + c) * L + l] = acc * sigm(acc);
}

// ---------- reverse second half channels along L: xb[b,c,l] = xm[b,64+c,L-1-l] ----------
__global__ void k_reverse(const float* __restrict__ xm, float* __restrict__ xb) {
  int t = blockIdx.x * TPB + threadIdx.x;   // B*HALF*L
  int l = t % L, c = (t / L) % HALF, b = t / (HALF * L);
  xb[t] = xm[((size_t)b * C + HALF + c) * L + (L - 1 - l)];
}

// ---------- uncertainty per pixel ----------
__global__ void k_unc(const float* __restrict__ xm, float* __restrict__ unc) {
  int p = blockIdx.x * TPB + threadIdx.x;   // B*L
  int b = p / L, l = p % L;
  const float* Xp = xm + (size_t)b * C * L + l;
  float s = 0.f;
  for (int c = 0; c < C; ++c) s += Xp[(size_t)c * L];
  float sg = sigm(s / C);
  unc[p] = -(sg * logf(sg + 1e-6f));
}

// ---------- stable argsort(-unc): bitonic on composite keys ----------
__global__ void k_sort(const float* __restrict__ unc, int* __restrict__ idx,
                       int* __restrict__ inv) {
  __shared__ unsigned long long s[L];
  int b = blockIdx.x;
  for (int i = threadIdx.x; i < L; i += blockDim.x) {
    unsigned u = __float_as_uint(unc[b * L + i]);
    u = (u & 0x80000000u) ? ~u : (u | 0x80000000u);  // monotone ascending map
    unsigned key = ~u;                                // descending unc
    s[i] = ((unsigned long long)key << 32) | (unsigned)i;
  }
  __syncthreads();
  for (int k = 2; k <= L; k <<= 1) {
    for (int j = k >> 1; j > 0; j >>= 1) {
      for (int i = threadIdx.x; i < L; i += blockDim.x) {
        int ixj = i ^ j;
        if (ixj > i) {
          unsigned long long a = s[i], bb = s[ixj];
          bool up = ((i & k) == 0);
          if ((a > bb) == up) { s[i] = bb; s[ixj] = a; }
        }
      }
      __syncthreads();
    }
  }
  for (int i = threadIdx.x; i < L; i += blockDim.x) {
    int orig = (int)(s[i] & 0xffffffffu);
    idx[b * L + i] = orig;
    inv[b * L + orig] = i;
  }
}

// ---------- gather xs[b,c,k] = xm[b,c,idx[b,k]] ----------
__global__ void k_gather(const float* __restrict__ xm, const int* __restrict__ idx,
                         float* __restrict__ xs) {
  int t = blockIdx.x * TPB + threadIdx.x;   // B*C*L
  int k = t % L, c = (t / L) % C, b = t / (C * L);
  xs[t] = xm[((size_t)b * C + c) * L + idx[b * L + k]];
}

// ---------- yu[b,c,l] = yus[b,c,inv[b,l]] ----------
__global__ void k_unsort(const float* __restrict__ yus, const int* __restrict__ inv,
                         float* __restrict__ yu) {
  int t = blockIdx.x * TPB + threadIdx.x;   // B*C*L
  int l = t % L, c = (t / L) % C, b = t / (C * L);
  yu[t] = yus[((size_t)b * C + c) * L + inv[b * L + l]];
}

// ---------- dt: scrambled reshape + double bias + softplus; dtu = dts*u ----------
// dt_used[b,c2,l2] = softplus( sum_r Wdt[csrc,r]*xdbl[b,lsrc,r] + bdt[csrc] + bdt[c2] )
// where f=c2*L+l2, lsrc=f/Cs, csrc=f%Cs  (row-major reshape of (B*L,Cs) to (B,Cs,L))
__global__ void k_dt(const float* __restrict__ xdbl, int O, int R,
                     const float* __restrict__ Wdt, const float* __restrict__ bdt,
                     const float* __restrict__ U, int ubs,
                     float* __restrict__ dts, float* __restrict__ dtu, int Cs) {
  int c2 = blockIdx.y, b = blockIdx.z;
  int l2 = blockIdx.x * TPB + threadIdx.x;
  int f = c2 * L + l2;
  int lsrc = f / Cs, csrc = f % Cs;
  const float* xr = xdbl + ((size_t)b * L + lsrc) * O;
  float acc = bdt[csrc] + bdt[c2];
  for (int r = 0; r < R; ++r) acc += Wdt[csrc * R + r] * xr[r];
  float d = softplusf(acc);
  size_t o = ((size_t)b * Cs + c2) * L + l2;
  dts[o] = d;
  dtu[o] = d * U[(size_t)b * ubs + (size_t)c2 * L + l2];
}

// ---------- Bm/Cm with scrambled reshape: (B*L,N) -> (B,N,L) ----------
__global__ void k_bc(const float* __restrict__ xdbl, int O, int R,
                     float* __restrict__ Bm, float* __restrict__ Cm) {
  int t = blockIdx.x * TPB + threadIdx.x;   // B*N*L
  int l = t % L, n = (t / L) % N, b = t / (N * L);
  int f = n * L + l;
  int lb = f >> 4, cb = f & 15;
  const float* xr = xdbl + ((size_t)b * L + lb) * O + R + cb;
  Bm[t] = xr[0];
  Cm[t] = xr[N];
}

// ---------- scan phase 1: per-chunk prod(dA) and partial h ----------
__global__ void k_scan1(const float* __restrict__ dts, const float* __restrict__ dtu,
                        const float* __restrict__ Bm, const float* __restrict__ Alog,
                        float* __restrict__ Ap, float* __restrict__ Hp, int Cs) {
  int t = blockIdx.x * TPB + threadIdx.x;   // B*Cs*NC
  int chunk = t & (NC - 1);
  int c = (t >> 6) % Cs;
  int b = t / (NC * Cs);
  float a[N], h[N], ap[N];
#pragma unroll
  for (int n = 0; n < N; ++n) {
    a[n] = -expf(Alog[c * N + n]);
    h[n] = 0.f; ap[n] = 1.f;
  }
  size_t rowoff = ((size_t)b * Cs + c) * L + chunk * CS;
  const float* dp = dts + rowoff;
  const float* up = dtu + rowoff;
  const float* bp = Bm + (size_t)b * N * L + chunk * CS;
  for (int s = 0; s < CS; ++s) {
    float d = dp[s], du = up[s];
#pragma unroll
    for (int n = 0; n < N; ++n) {
      float dA = expf(d * a[n]);
      ap[n] *= dA;
      h[n] = h[n] * dA + du * bp[(size_t)n * L + s];
    }
  }
  size_t base = ((size_t)b * Cs + c) * N * NC + chunk;
#pragma unroll
  for (int n = 0; n < N; ++n) { Ap[base + n * NC] = ap[n]; Hp[base + n * NC] = h[n]; }
}

// ---------- scan phase 2: cross-chunk recurrence ----------
__global__ void k_scan2(const float* __restrict__ Ap, const float* __restrict__ Hp,
                        float* __restrict__ Hs) {
  int t = blockIdx.x * TPB + threadIdx.x;   // B*Cs*N rows, each NC long
  size_t base = (size_t)t * NC;
  float hs = 0.f;
  Hs[base] = 0.f;
  for (int k = 1; k < NC; ++k) {
    hs = Ap[base + k - 1] * hs + Hp[base + k - 1];
    Hs[base + k] = hs;
  }
}

// ---------- scan phase 3: replay with correct h_start; y = h.C + u*D ----------
__global__ void k_scan3(const float* __restrict__ dts, const float* __restrict__ dtu,
                        const float* __restrict__ Bm, const float* __restrict__ Cmm,
                        const float* __restrict__ Alog, const float* __restrict__ Hs,
                        const float* __restrict__ U, int ubs, const float* __restrict__ D,
                        float* __restrict__ Y, int Cs) {
  int t = blockIdx.x * TPB + threadIdx.x;
  int chunk = t & (NC - 1);
  int c = (t >> 6) % Cs;
  int b = t / (NC * Cs);
  float a[N], h[N];
  size_t hbase = ((size_t)b * Cs + c) * N * NC + chunk;
#pragma unroll
  for (int n = 0; n < N; ++n) {
    a[n] = -expf(Alog[c * N + n]);
    h[n] = Hs[hbase + n * NC];
  }
  size_t rowoff = ((size_t)b * Cs + c) * L + chunk * CS;
  const float* dp = dts + rowoff;
  const float* up = dtu + rowoff;
  const float* bp = Bm + (size_t)b * N * L + chunk * CS;
  const float* cp = Cmm + (size_t)b * N * L + chunk * CS;
  const float* uu = U + (size_t)b * ubs + (size_t)c * L + chunk * CS;
  float Dc = D[c];
  float* yp = Y + rowoff;
  for (int s = 0; s < CS; ++s) {
    float d = dp[s], du = up[s];
    float y = 0.f;
#pragma unroll
    for (int n = 0; n < N; ++n) {
      float dA = expf(d * a[n]);
      h[n] = h[n] * dA + du * bp[(size_t)n * L + s];
      y += h[n] * cp[(size_t)n * L + s];
    }
    yp[s] = y + uu[s] * Dc;
  }
}

// ---------- BN train-mode stats -> per-channel scale/shift ----------
__global__ void k_bn_stats(const float* __restrict__ X, const float* __restrict__ g,
                           const float* __restrict__ bb, float* __restrict__ scale,
                           float* __restrict__ shift) {
  int c = blockIdx.x;
  float s = 0.f, s2 = 0.f;
  for (int t = threadIdx.x; t < B_SZ * L; t += TPB) {
    int b = t / L, l = t % L;
    float v = X[((size_t)b * C + c) * L + l];
    s += v; s2 += v * v;
  }
  __shared__ float r1[TPB], r2[TPB];
  r1[threadIdx.x] = s; r2[threadIdx.x] = s2;
  __syncthreads();
  for (int off = TPB / 2; off > 0; off >>= 1) {
    if (threadIdx.x < off) {
      r1[threadIdx.x] += r1[threadIdx.x + off];
      r2[threadIdx.x] += r2[threadIdx.x + off];
    }
    __syncthreads();
  }
  if (threadIdx.x == 0) {
    float mean = r1[0] / (B_SZ * L);
    float var  = r2[0] / (B_SZ * L) - mean * mean;
    float sc = g[c] * rsqrtf(var + 1e-5f);
    scale[c] = sc;
    shift[c] = bb[c] - mean * sc;
  }
}

__global__ void k_bn_relu(float* __restrict__ X, const float* __restrict__ scale,
                          const float* __restrict__ shift) {
  int t = blockIdx.x * TPB + threadIdx.x;   // B*C*L
  int c = (t / L) % C;
  float v = scale[c] * X[t] + shift[c];
  X[t] = fmaxf(v, 0.f);
}

__global__ void k_fuse(const float* __restrict__ g, const float* __restrict__ yu,
                       const float* __restrict__ cat, float* __restrict__ out) {
  int t = blockIdx.x * TPB + threadIdx.x;
  float gv = g[t];
  out[t] = gv * yu[t] + (1.f - gv) * cat[t];
}

} // namespace

extern "C" void kernel_launch(void* const* d_in, const int* in_sizes, int n_in,
                              void* d_out, int out_size, void* d_ws, size_t ws_size,
                              hipStream_t stream) {
  const float* x         = (const float*)d_in[0];
  const float* ln_in_w   = (const float*)d_in[1];
  const float* ln_in_b   = (const float*)d_in[2];
  const float* inproj_w  = (const float*)d_in[3];
  const float* inproj_b  = (const float*)d_in[4];
  const float* ln_m_w    = (const float*)d_in[5];
  const float* ln_m_b    = (const float*)d_in[6];
  const float* convm_w   = (const float*)d_in[7];
  const float* convm_b   = (const float*)d_in[8];
  const float* convr_w   = (const float*)d_in[9];
  const float* convr_b   = (const float*)d_in[10];
  const float* ln_cat_w  = (const float*)d_in[11];
  const float* ln_cat_b  = (const float*)d_in[12];
  const float* xpf_w     = (const float*)d_in[13];
  const float* xpf_b     = (const float*)d_in[14];
  const float* dtf_w     = (const float*)d_in[15];
  const float* dtf_b     = (const float*)d_in[16];
  const float* Alog_f    = (const float*)d_in[17];
  const float* D_f       = (const float*)d_in[18];
  const float* xpb_w     = (const float*)d_in[19];
  const float* xpb_b     = (const float*)d_in[20];
  const float* dtb_w     = (const float*)d_in[21];
  const float* dtb_b     = (const float*)d_in[22];
  const float* Alog_b    = (const float*)d_in[23];
  const float* D_b       = (const float*)d_in[24];
  const float* xpu_w     = (const float*)d_in[25];
  const float* xpu_b     = (const float*)d_in[26];
  const float* dtu_w     = (const float*)d_in[27];
  const float* dtu_b     = (const float*)d_in[28];
  const float* Alog_u    = (const float*)d_in[29];
  const float* D_u       = (const float*)d_in[30];
  const float* gate1_w   = (const float*)d_in[31];
  const float* gate1_b   = (const float*)d_in[32];
  const float* bn_g      = (const float*)d_in[33];
  const float* bn_b      = (const float*)d_in[34];
  const float* gate2_w   = (const float*)d_in[35];
  const float* gate2_b   = (const float*)d_in[36];
  const float* outproj_w = (const float*)d_in[37];
  const float* outproj_b = (const float*)d_in[38];
  const float* outln_w   = (const float*)d_in[39];
  const float* outln_b   = (const float*)d_in[40];

  float* ws = (float*)d_ws;
  size_t off = 0;
  auto alloc = [&](size_t n) { float* p = ws + off; off += n; return p; };

  float* x_ln  = alloc((size_t)B_SZ * C * L);
  float* xp    = alloc((size_t)B_SZ * 2 * C * L);
  float* xlnm  = alloc((size_t)B_SZ * C * L);
  float* xm    = alloc((size_t)B_SZ * C * L);
  float* xr    = alloc((size_t)B_SZ * C * L);
  float* xb    = alloc((size_t)B_SZ * HALF * L);
  float* unc   = alloc((size_t)B_SZ * L);
  int*   idx   = (int*)alloc((size_t)B_SZ * L);
  int*   inv   = (int*)alloc((size_t)B_SZ * L);
  float* xs    = alloc((size_t)B_SZ * C * L);
  // scan scratch (shared across the three scans; launches serialize on stream)
  float* xdbl  = alloc((size_t)B_SZ * L * 40);
  float* dts   = alloc((size_t)B_SZ * C * L);
  float* dtub  = alloc((size_t)B_SZ * C * L);
  float* Bm    = alloc((size_t)B_SZ * N * L);
  float* Cm    = alloc((size_t)B_SZ * N * L);
  float* Ap    = alloc((size_t)B_SZ * C * N * NC);
  float* Hp    = alloc((size_t)B_SZ * C * N * NC);
  float* Hs    = alloc((size_t)B_SZ * C * N * NC);
  // persistent outputs
  float* yf    = alloc((size_t)B_SZ * HALF * L);
  float* yb    = alloc((size_t)B_SZ * HALF * L);
  float* yus   = alloc((size_t)B_SZ * C * L);
  float* yu    = alloc((size_t)B_SZ * C * L);
  float* cat   = alloc((size_t)B_SZ * C * L);
  float* g1    = alloc((size_t)B_SZ * C * L);
  float* bnsc  = alloc(256);
  float* g     = alloc((size_t)B_SZ * C * L);
  float* fused = alloc((size_t)B_SZ * C * L);
  float* outp  = alloc((size_t)B_SZ * C * L);
  (void)ws_size; (void)in_sizes; (void)n_in; (void)out_size;

  const int pixB = B_SZ * L / TPB;         // 32
  const int elemB = B_SZ * C * L / TPB;    // 4096

  // 1) LN in
  k_ln_cf<<<pixB, TPB, 0, stream>>>(x, C * L, ln_in_w, ln_in_b, x_ln, C * L, C, 1e-6f);
  // 2) inproj 128 -> 256
  k_conv1x1<8, 0, false><<<dim3(L / TPB, 256 / 8, B_SZ), TPB, 0, stream>>>(
      x_ln, C * L, inproj_w, inproj_b, xp, 128, 256);
  // 3) LN mamba on first 128 channels of xp
  k_ln_cf<<<pixB, TPB, 0, stream>>>(xp, 2 * C * L, ln_m_w, ln_m_b, xlnm, C * L, C, 1e-6f);
  // 4) depthwise conv + silu
  k_dwconv_silu<<<dim3(L / TPB, C, B_SZ), TPB, 0, stream>>>(xlnm, C * L, convm_w, convm_b, xm);
  k_dwconv_silu<<<dim3(L / TPB, C, B_SZ), TPB, 0, stream>>>(xp + (size_t)C * L, 2 * C * L,
                                                            convr_w, convr_b, xr);
  // 5) reversed second-half channels
  k_reverse<<<B_SZ * HALF * L / TPB, TPB, 0, stream>>>(xm, xb);
  // 6) uncertainty + stable sort + gather
  k_unc<<<pixB, TPB, 0, stream>>>(xm, unc);
  k_sort<<<B_SZ, 1024, 0, stream>>>(unc, idx, inv);
  k_gather<<<elemB, TPB, 0, stream>>>(xm, idx, xs);

  // ---- selective scans ----
  auto run_scan = [&](const float* U, int ubs, int Cs, int R,
                      const float* Wx, const float* bx,
                      const float* Wdt, const float* bdt,
                      const float* Alog, const float* D, float* Y) {
    int O = R + 2 * N;
    k_conv1x1<4, 0, true><<<dim3(L / TPB, O / 4, B_SZ), TPB, 0, stream>>>(
        U, ubs, Wx, bx, xdbl, Cs, O);
    k_dt<<<dim3(L / TPB, Cs, B_SZ), TPB, 0, stream>>>(xdbl, O, R, Wdt, bdt, U, ubs,
                                                      dts, dtub, Cs);
    k_bc<<<B_SZ * N * L / TPB, TPB, 0, stream>>>(xdbl, O, R, Bm, Cm);
    int n13 = B_SZ * Cs * NC / TPB;
    k_scan1<<<n13, TPB, 0, stream>>>(dts, dtub, Bm, Alog, Ap, Hp, Cs);
    k_scan2<<<B_SZ * Cs * N / TPB, TPB, 0, stream>>>(Ap, Hp, Hs);
    k_scan3<<<n13, TPB, 0, stream>>>(dts, dtub, Bm, Cm, Alog, Hs, U, ubs, D, Y, Cs);
  };

  run_scan(xm, C * L, HALF, 4, xpf_w, xpf_b, dtf_w, dtf_b, Alog_f, D_f, yf);
  run_scan(xb, HALF * L, HALF, 4, xpb_w, xpb_b, dtb_w, dtb_b, Alog_b, D_b, yb);
  run_scan(xs, C * L, C, 8, xpu_w, xpu_b, dtu_w, dtu_b, Alog_u, D_u, yus);

  // 7) LN(concat([yf, reverse(yb)]))
  k_ln_cat<<<pixB, TPB, 0, stream>>>(yf, yb, ln_cat_w, ln_cat_b, cat);
  // 8) unsort yu
  k_unsort<<<elemB, TPB, 0, stream>>>(yus, inv, yu);
  // 9) gate1 (256 -> 128), BN(train) + relu, gate2 (128 -> 128) + sigmoid
  k_conv1x1_cat2<8, 0><<<dim3(L / TPB, 128 / 8, B_SZ), TPB, 0, stream>>>(
      cat, C * L, yu, C * L, gate1_w, gate1_b, g1, 128);
  k_bn_stats<<<C, TPB, 0, stream>>>(g1, bn_g, bn_b, bnsc, bnsc + 128);
  k_bn_relu<<<elemB, TPB, 0, stream>>>(g1, bnsc, bnsc + 128);
  k_conv1x1<8, 1, false><<<dim3(L / TPB, 128 / 8, B_SZ), TPB, 0, stream>>>(
      g1, C * L, gate2_w, gate2_b, g, 128, 128);
  // 10) fused = g*yu + (1-g)*cat
  k_fuse<<<elemB, TPB, 0, stream>>>(g, yu, cat, fused);
  // 11) outproj (concat([fused, xr]) -> 128) + final LN -> d_out
  k_conv1x1_cat2<8, 0><<<dim3(L / TPB, 128 / 8, B_SZ), TPB, 0, stream>>>(
      fused, C * L, xr, C * L, outproj_w, outproj_b, outp, 128);
  k_ln_cf<<<pixB, TPB, 0, stream>>>(outp, C * L, outln_w, outln_b, (float*)d_out,
                                    C * L, C, 1e-6f);
}

// Round 2
// 617.777 us; speedup vs baseline: 2.9829x; 2.9829x over previous
//
#include <hip/hip_runtime.h>
#include <cstdint>
#include <cstddef>

#define TPB 256
#define TPB_PIX 64

namespace {

constexpr int B_SZ = 2;
constexpr int C    = 128;
constexpr int HALF = 64;
constexpr int L    = 4096;   // 64*64
constexpr int N    = 16;
constexpr int HH   = 64;
constexpr int WW   = 64;
constexpr int NC   = 64;     // number of chunks
constexpr int CS   = 64;     // chunk size (NC*CS == L)

__device__ __forceinline__ float softplusf(float x) {
  return fmaxf(x, 0.f) + log1pf(expf(-fabsf(x)));
}
__device__ __forceinline__ float sigm(float x) { return 1.f / (1.f + expf(-x)); }

// ---------- channel-first LayerNorm, one thread per pixel ----------
__global__ void k_ln_cf(const float* __restrict__ X, int bsX,
                        const float* __restrict__ w, const float* __restrict__ bchan,
                        float* __restrict__ Y, int bsY, int Cn, float eps) {
  int p = blockIdx.x * TPB_PIX + threadIdx.x;  // p in [0, B*L)
  int b = p / L, l = p % L;
  const float* Xp = X + (size_t)b * bsX + l;
  float s = 0.f, s2 = 0.f;
  for (int c = 0; c < Cn; ++c) { float v = Xp[(size_t)c * L]; s += v; s2 += v * v; }
  float mean = s / Cn;
  float var  = s2 / Cn - mean * mean;
  float rinv = rsqrtf(var + eps);
  float* Yp = Y + (size_t)b * bsY + l;
  for (int c = 0; c < Cn; ++c) {
    float v = Xp[(size_t)c * L];
    Yp[(size_t)c * L] = w[c] * (v - mean) * rinv + bchan[c];
  }
}

// ---------- LN over concat([yf, reverse_L(yb)]) ----------
__global__ void k_ln_cat(const float* __restrict__ yf, const float* __restrict__ ybr,
                         const float* __restrict__ w, const float* __restrict__ bchan,
                         float* __restrict__ Y) {
  int p = blockIdx.x * TPB_PIX + threadIdx.x;
  int b = p / L, l = p % L;
  const float* f0 = yf  + (size_t)b * HALF * L + l;
  const float* b0 = ybr + (size_t)b * HALF * L + (L - 1 - l);
  float s = 0.f, s2 = 0.f;
  for (int c = 0; c < HALF; ++c) { float v = f0[(size_t)c * L]; s += v; s2 += v * v; }
  for (int c = 0; c < HALF; ++c) { float v = b0[(size_t)c * L]; s += v; s2 += v * v; }
  float mean = s / C, var = s2 / C - mean * mean;
  float rinv = rsqrtf(var + 1e-6f);
  float* Yp = Y + (size_t)b * C * L + l;
  for (int c = 0; c < HALF; ++c) {
    float v = f0[(size_t)c * L];
    Yp[(size_t)c * L] = w[c] * (v - mean) * rinv + bchan[c];
  }
  for (int c = 0; c < HALF; ++c) {
    float v = b0[(size_t)c * L];
    Yp[(size_t)(HALF + c) * L] = w[HALF + c] * (v - mean) * rinv + bchan[HALF + c];
  }
}

// ---------- 1x1 conv: Y[b,o,l] = sum_i W[o,i]*X[b,i,l] + bias[o] ----------
template <int O_PB, int EPI, bool BLO>
__global__ void k_conv1x1(const float* __restrict__ X, int bsX,
                          const float* __restrict__ W, const float* __restrict__ bias,
                          float* __restrict__ Y, int I, int O) {
  __shared__ float Wl[O_PB * 256];
  const int o0 = blockIdx.y * O_PB;
  const int b  = blockIdx.z;
  for (int t = threadIdx.x; t < O_PB * I; t += TPB) {
    int i = t / O_PB, k = t % O_PB;
    Wl[t] = W[(size_t)(o0 + k) * I + i];
  }
  __syncthreads();
  const int l = blockIdx.x * TPB + threadIdx.x;
  const float* Xb = X + (size_t)b * bsX + l;
  float acc[O_PB];
#pragma unroll
  for (int k = 0; k < O_PB; ++k) acc[k] = bias[o0 + k];
#pragma unroll 4
  for (int i = 0; i < I; ++i) {
    float xv = Xb[(size_t)i * L];
#pragma unroll
    for (int k = 0; k < O_PB; ++k) acc[k] += Wl[i * O_PB + k] * xv;
  }
#pragma unroll
  for (int k = 0; k < O_PB; ++k) {
    float v = acc[k];
    if (EPI == 1) v = sigm(v);
    if (BLO) Y[((size_t)b * L + l) * O + o0 + k] = v;
    else     Y[((size_t)b * O + o0 + k) * L + l] = v;
  }
}

// ---------- 1x1 conv over concat of two (B,128,L) tensors ----------
template <int O_PB, int EPI>
__global__ void k_conv1x1_cat2(const float* __restrict__ X1, int bs1,
                               const float* __restrict__ X2, int bs2,
                               const float* __restrict__ W, const float* __restrict__ bias,
                               float* __restrict__ Y, int O) {
  __shared__ float Wl[O_PB * 256];
  const int o0 = blockIdx.y * O_PB;
  const int b  = blockIdx.z;
  for (int t = threadIdx.x; t < O_PB * 256; t += TPB) {
    int i = t / O_PB, k = t % O_PB;
    Wl[t] = W[(size_t)(o0 + k) * 256 + i];
  }
  __syncthreads();
  const int l = blockIdx.x * TPB + threadIdx.x;
  const float* Xb1 = X1 + (size_t)b * bs1 + l;
  const float* Xb2 = X2 + (size_t)b * bs2 + l;
  float acc[O_PB];
#pragma unroll
  for (int k = 0; k < O_PB; ++k) acc[k] = bias[o0 + k];
#pragma unroll 4
  for (int i = 0; i < 128; ++i) {
    float xv = Xb1[(size_t)i * L];
#pragma unroll
    for (int k = 0; k < O_PB; ++k) acc[k] += Wl[i * O_PB + k] * xv;
  }
#pragma unroll 4
  for (int i = 0; i < 128; ++i) {
    float xv = Xb2[(size_t)i * L];
#pragma unroll
    for (int k = 0; k < O_PB; ++k) acc[k] += Wl[(128 + i) * O_PB + k] * xv;
  }
#pragma unroll
  for (int k = 0; k < O_PB; ++k) {
    float v = acc[k];
    if (EPI == 1) v = sigm(v);
    Y[((size_t)b * O + o0 + k) * L + l] = v;
  }
}

// ---------- depthwise 3x3 SAME + bias + SiLU ----------
__global__ void k_dwconv_silu(const float* __restrict__ X, int bsX,
                              const float* __restrict__ W9, const float* __restrict__ bias,
                              float* __restrict__ Y) {
  int c = blockIdx.y, b = blockIdx.z;
  int l = blockIdx.x * TPB + threadIdx.x;
  int h = l / WW, w = l % WW;
  const float* Xc = X + (size_t)b * bsX + (size_t)c * L;
  float acc = bias[c];
#pragma unroll
  for (int kh = 0; kh < 3; ++kh) {
    int hh = h + kh - 1;
    if (hh < 0 || hh >= HH) continue;
#pragma unroll
    for (int kw = 0; kw < 3; ++kw) {
      int ww2 = w + kw - 1;
      if (ww2 < 0 || ww2 >= WW) continue;
      acc += Xc[hh * WW + ww2] * W9[c * 9 + kh * 3 + kw];
    }
  }
  Y[((size_t)b * C + c) * L + l] = acc * sigm(acc);
}

// ---------- reverse second half channels along L ----------
__global__ void k_reverse(const float* __restrict__ xm, float* __restrict__ xb) {
  int t = blockIdx.x * TPB + threadIdx.x;   // B*HALF*L
  int l = t % L, c = (t / L) % HALF, b = t / (HALF * L);
  xb[t] = xm[((size_t)b * C + HALF + c) * L + (L - 1 - l)];
}

// ---------- uncertainty per pixel ----------
__global__ void k_unc(const float* __restrict__ xm, float* __restrict__ unc) {
  int p = blockIdx.x * TPB_PIX + threadIdx.x;   // B*L
  int b = p / L, l = p % L;
  const float* Xp = xm + (size_t)b * C * L + l;
  float s = 0.f;
  for (int c = 0; c < C; ++c) s += Xp[(size_t)c * L];
  float sg = sigm(s / C);
  unc[p] = -(sg * logf(sg + 1e-6f));
}

// ---------- stable argsort(-unc): bitonic on composite keys ----------
__global__ void k_sort(const float* __restrict__ unc, int* __restrict__ idx,
                       int* __restrict__ inv) {
  __shared__ unsigned long long s[L];
  int b = blockIdx.x;
  for (int i = threadIdx.x; i < L; i += blockDim.x) {
    unsigned u = __float_as_uint(unc[b * L + i]);
    u = (u & 0x80000000u) ? ~u : (u | 0x80000000u);  // monotone ascending map
    unsigned key = ~u;                                // descending unc
    s[i] = ((unsigned long long)key << 32) | (unsigned)i;
  }
  __syncthreads();
  for (int k = 2; k <= L; k <<= 1) {
    for (int j = k >> 1; j > 0; j >>= 1) {
      for (int i = threadIdx.x; i < L; i += blockDim.x) {
        int ixj = i ^ j;
        if (ixj > i) {
          unsigned long long a = s[i], bb = s[ixj];
          bool up = ((i & k) == 0);
          if ((a > bb) == up) { s[i] = bb; s[ixj] = a; }
        }
      }
      __syncthreads();
    }
  }
  for (int i = threadIdx.x; i < L; i += blockDim.x) {
    int orig = (int)(s[i] & 0xffffffffu);
    idx[b * L + i] = orig;
    inv[b * L + orig] = i;
  }
}

// ---------- gather / unsort ----------
__global__ void k_gather(const float* __restrict__ xm, const int* __restrict__ idx,
                         float* __restrict__ xs) {
  int t = blockIdx.x * TPB + threadIdx.x;   // B*C*L
  int k = t % L, c = (t / L) % C, b = t / (C * L);
  xs[t] = xm[((size_t)b * C + c) * L + idx[b * L + k]];
}

__global__ void k_unsort(const float* __restrict__ yus, const int* __restrict__ inv,
                         float* __restrict__ yu) {
  int t = blockIdx.x * TPB + threadIdx.x;   // B*C*L
  int l = t % L, c = (t / L) % C, b = t / (C * L);
  yu[t] = yus[((size_t)b * C + c) * L + inv[b * L + l]];
}

// ---------- dt: scrambled reshape + double bias + softplus; dtu = dts*u ----------
__global__ void k_dt(const float* __restrict__ xdbl, int O, int R,
                     const float* __restrict__ Wdt, const float* __restrict__ bdt,
                     const float* __restrict__ U, int ubs,
                     float* __restrict__ dts, float* __restrict__ dtu, int Cs) {
  int c2 = blockIdx.y, b = blockIdx.z;
  int l2 = blockIdx.x * TPB + threadIdx.x;
  int f = c2 * L + l2;
  int lsrc = f / Cs, csrc = f % Cs;
  const float* xr = xdbl + ((size_t)b * L + lsrc) * O;
  float acc = bdt[csrc] + bdt[c2];
  for (int r = 0; r < R; ++r) acc += Wdt[csrc * R + r] * xr[r];
  float d = softplusf(acc);
  size_t o = ((size_t)b * Cs + c2) * L + l2;
  dts[o] = d;
  dtu[o] = d * U[(size_t)b * ubs + (size_t)c2 * L + l2];
}

// ---------- Bm/Cm scrambled reshape -> TRANSPOSED (B, L, N) layout ----------
// BmT[b, l, n] = Bm[b, n, l] of the reference; same for CmT.
__global__ void k_bc_t(const float* __restrict__ xdbl, int O, int R,
                       float* __restrict__ BmT, float* __restrict__ CmT) {
  int t = blockIdx.x * TPB + threadIdx.x;   // B*L*N
  int n = t & 15, l = (t >> 4) & (L - 1), b = t >> 16;
  int f = n * L + l;
  int lb = f >> 4, cb = f & 15;
  const float* xr = xdbl + ((size_t)b * L + lb) * O + R + cb;
  BmT[t] = xr[0];
  CmT[t] = xr[N];
}

// ---------- scan phase 1: thread = (b, c, n, chunk); n in low 4 lane bits ----------
__global__ void k_scan1(const float* __restrict__ dts, const float* __restrict__ dtu,
                        const float* __restrict__ BmT, const float* __restrict__ Alog,
                        float* __restrict__ Ap, float* __restrict__ Hp, int Cs) {
  int t = blockIdx.x * TPB + threadIdx.x;
  int n = t & 15;
  int chunk = (t >> 4) & (NC - 1);
  int rc = t >> 10;                 // b*Cs + c
  int c = rc % Cs, b = rc / Cs;
  float a = -expf(Alog[c * N + n]);
  float ap = 1.f, h = 0.f;
  size_t rowoff = (size_t)rc * L + chunk * CS;
  const float4* dp4 = (const float4*)(dts + rowoff);
  const float4* up4 = (const float4*)(dtu + rowoff);
  const float* bp = BmT + (((size_t)b * L + chunk * CS) << 4) + n;
#pragma unroll
  for (int j = 0; j < CS / 4; ++j) {
    float4 d4 = dp4[j], du4 = up4[j];
    float dv[4] = {d4.x, d4.y, d4.z, d4.w};
    float uv[4] = {du4.x, du4.y, du4.z, du4.w};
#pragma unroll
    for (int jj = 0; jj < 4; ++jj) {
      int s = 4 * j + jj;
      float bn = bp[(size_t)s << 4];
      float dA = expf(dv[jj] * a);
      ap *= dA;
      h = h * dA + uv[jj] * bn;
    }
  }
  size_t base = ((size_t)rc * N + n) * NC + chunk;
  Ap[base] = ap;
  Hp[base] = h;
}

// ---------- scan phase 2: wave-parallel log-scan over chunks ----------
// row = (b*Cs+c)*N + n; lane k = chunk. Hs[k] = exclusive scan of (Ap,Hp).
__global__ void k_scan2(const float* __restrict__ Ap, const float* __restrict__ Hp,
                        float* __restrict__ Hs) {
  int t = blockIdx.x * TPB + threadIdx.x;
  int k = t & 63;
  size_t row = (size_t)(t >> 6) * NC;
  float A = Ap[row + k];
  float B = Hp[row + k];
#pragma unroll
  for (int j = 1; j < NC; j <<= 1) {
    float pa = __shfl_up(A, j);
    float pb = __shfl_up(B, j);
    if (k >= j) { B = pb * A + B; A = pa * A; }
  }
  float hprev = __shfl_up(B, 1);
  Hs[row + k] = (k == 0) ? 0.f : hprev;
}

// ---------- scan phase 3: replay with h_start; y = sum_n h*C + u*D ----------
__global__ void k_scan3(const float* __restrict__ dts, const float* __restrict__ dtu,
                        const float* __restrict__ BmT, const float* __restrict__ CmT,
                        const float* __restrict__ Alog, const float* __restrict__ Hs,
                        const float* __restrict__ U, int ubs, const float* __restrict__ D,
                        float* __restrict__ Y, int Cs) {
  int t = blockIdx.x * TPB + threadIdx.x;
  int n = t & 15;
  int chunk = (t >> 4) & (NC - 1);
  int rc = t >> 10;
  int c = rc % Cs, b = rc / Cs;
  float a = -expf(Alog[c * N + n]);
  float h = Hs[((size_t)rc * N + n) * NC + chunk];
  float Dc = D[c];
  size_t rowoff = (size_t)rc * L + chunk * CS;
  const float4* dp4 = (const float4*)(dts + rowoff);
  const float4* up4 = (const float4*)(dtu + rowoff);
  const float4* uu4 = (const float4*)(U + (size_t)b * ubs + (size_t)c * L + chunk * CS);
  const float* bp = BmT + (((size_t)b * L + chunk * CS) << 4) + n;
  const float* cp = CmT + (((size_t)b * L + chunk * CS) << 4) + n;
  float ybuf[4];
#pragma unroll
  for (int j = 0; j < CS / 4; ++j) {
    float4 d4 = dp4[j], du4 = up4[j], u4 = uu4[j];
    float dv[4] = {d4.x, d4.y, d4.z, d4.w};
    float uv[4] = {du4.x, du4.y, du4.z, du4.w};
    float xv[4] = {u4.x, u4.y, u4.z, u4.w};
#pragma unroll
    for (int jj = 0; jj < 4; ++jj) {
      int s = 4 * j + jj;
      float bn = bp[(size_t)s << 4];
      float cn = cp[(size_t)s << 4];
      float dA = expf(dv[jj] * a);
      h = h * dA + uv[jj] * bn;
      float p = h * cn;
      p += __shfl_xor(p, 1);
      p += __shfl_xor(p, 2);
      p += __shfl_xor(p, 4);
      p += __shfl_xor(p, 8);
      float yv = p + xv[jj] * Dc;
      if ((s & 15) == n) ybuf[s >> 4] = yv;
    }
  }
  float* yp = Y + rowoff;
#pragma unroll
  for (int q = 0; q < 4; ++q) yp[16 * q + n] = ybuf[q];
}

// ---------- BN train-mode stats -> per-channel scale/shift ----------
__global__ void k_bn_stats(const float* __restrict__ X, const float* __restrict__ g,
                           const float* __restrict__ bb, float* __restrict__ scale,
                           float* __restrict__ shift) {
  int c = blockIdx.x;
  float s = 0.f, s2 = 0.f;
  for (int t = threadIdx.x; t < B_SZ * L; t += TPB) {
    int b = t / L, l = t % L;
    float v = X[((size_t)b * C + c) * L + l];
    s += v; s2 += v * v;
  }
  __shared__ float r1[TPB], r2[TPB];
  r1[threadIdx.x] = s; r2[threadIdx.x] = s2;
  __syncthreads();
  for (int off = TPB / 2; off > 0; off >>= 1) {
    if (threadIdx.x < off) {
      r1[threadIdx.x] += r1[threadIdx.x + off];
      r2[threadIdx.x] += r2[threadIdx.x + off];
    }
    __syncthreads();
  }
  if (threadIdx.x == 0) {
    float mean = r1[0] / (B_SZ * L);
    float var  = r2[0] / (B_SZ * L) - mean * mean;
    float sc = g[c] * rsqrtf(var + 1e-5f);
    scale[c] = sc;
    shift[c] = bb[c] - mean * sc;
  }
}

__global__ void k_bn_relu(float* __restrict__ X, const float* __restrict__ scale,
                          const float* __restrict__ shift) {
  int t = blockIdx.x * TPB + threadIdx.x;   // B*C*L
  int c = (t / L) % C;
  float v = scale[c] * X[t] + shift[c];
  X[t] = fmaxf(v, 0.f);
}

__global__ void k_fuse(const float* __restrict__ g, const float* __restrict__ yu,
                       const float* __restrict__ cat, float* __restrict__ out) {
  int t = blockIdx.x * TPB + threadIdx.x;
  float gv = g[t];
  out[t] = gv * yu[t] + (1.f - gv) * cat[t];
}

} // namespace

extern "C" void kernel_launch(void* const* d_in, const int* in_sizes, int n_in,
                              void* d_out, int out_size, void* d_ws, size_t ws_size,
                              hipStream_t stream) {
  const float* x         = (const float*)d_in[0];
  const float* ln_in_w   = (const float*)d_in[1];
  const float* ln_in_b   = (const float*)d_in[2];
  const float* inproj_w  = (const float*)d_in[3];
  const float* inproj_b  = (const float*)d_in[4];
  const float* ln_m_w    = (const float*)d_in[5];
  const float* ln_m_b    = (const float*)d_in[6];
  const float* convm_w   = (const float*)d_in[7];
  const float* convm_b   = (const float*)d_in[8];
  const float* convr_w   = (const float*)d_in[9];
  const float* convr_b   = (const float*)d_in[10];
  const float* ln_cat_w  = (const float*)d_in[11];
  const float* ln_cat_b  = (const float*)d_in[12];
  const float* xpf_w     = (const float*)d_in[13];
  const float* xpf_b     = (const float*)d_in[14];
  const float* dtf_w     = (const float*)d_in[15];
  const float* dtf_b     = (const float*)d_in[16];
  const float* Alog_f    = (const float*)d_in[17];
  const float* D_f       = (const float*)d_in[18];
  const float* xpb_w     = (const float*)d_in[19];
  const float* xpb_b     = (const float*)d_in[20];
  const float* dtb_w     = (const float*)d_in[21];
  const float* dtb_b     = (const float*)d_in[22];
  const float* Alog_b    = (const float*)d_in[23];
  const float* D_b       = (const float*)d_in[24];
  const float* xpu_w     = (const float*)d_in[25];
  const float* xpu_b     = (const float*)d_in[26];
  const float* dtu_w     = (const float*)d_in[27];
  const float* dtu_b     = (const float*)d_in[28];
  const float* Alog_u    = (const float*)d_in[29];
  const float* D_u       = (const float*)d_in[30];
  const float* gate1_w   = (const float*)d_in[31];
  const float* gate1_b   = (const float*)d_in[32];
  const float* bn_g      = (const float*)d_in[33];
  const float* bn_b      = (const float*)d_in[34];
  const float* gate2_w   = (const float*)d_in[35];
  const float* gate2_b   = (const float*)d_in[36];
  const float* outproj_w = (const float*)d_in[37];
  const float* outproj_b = (const float*)d_in[38];
  const float* outln_w   = (const float*)d_in[39];
  const float* outln_b   = (const float*)d_in[40];

  float* ws = (float*)d_ws;
  size_t off = 0;
  auto alloc = [&](size_t n) { float* p = ws + off; off += n; return p; };

  float* x_ln  = alloc((size_t)B_SZ * C * L);
  float* xp    = alloc((size_t)B_SZ * 2 * C * L);
  float* xlnm  = alloc((size_t)B_SZ * C * L);
  float* xm    = alloc((size_t)B_SZ * C * L);
  float* xr    = alloc((size_t)B_SZ * C * L);
  float* xb    = alloc((size_t)B_SZ * HALF * L);
  float* unc   = alloc((size_t)B_SZ * L);
  int*   idx   = (int*)alloc((size_t)B_SZ * L);
  int*   inv   = (int*)alloc((size_t)B_SZ * L);
  float* xs    = alloc((size_t)B_SZ * C * L);
  float* xdbl  = alloc((size_t)B_SZ * L * 40);
  float* dts   = alloc((size_t)B_SZ * C * L);
  float* dtub  = alloc((size_t)B_SZ * C * L);
  float* BmT   = alloc((size_t)B_SZ * N * L);
  float* CmT   = alloc((size_t)B_SZ * N * L);
  float* Ap    = alloc((size_t)B_SZ * C * N * NC);
  float* Hp    = alloc((size_t)B_SZ * C * N * NC);
  float* Hs    = alloc((size_t)B_SZ * C * N * NC);
  float* yf    = alloc((size_t)B_SZ * HALF * L);
  float* yb    = alloc((size_t)B_SZ * HALF * L);
  float* yus   = alloc((size_t)B_SZ * C * L);
  float* yu    = alloc((size_t)B_SZ * C * L);
  float* cat   = alloc((size_t)B_SZ * C * L);
  float* g1    = alloc((size_t)B_SZ * C * L);
  float* bnsc  = alloc(256);
  float* g     = alloc((size_t)B_SZ * C * L);
  float* fused = alloc((size_t)B_SZ * C * L);
  float* outp  = alloc((size_t)B_SZ * C * L);
  (void)ws_size; (void)in_sizes; (void)n_in; (void)out_size;

  const int pixB = B_SZ * L / TPB_PIX;     // 128
  const int elemB = B_SZ * C * L / TPB;    // 4096

  k_ln_cf<<<pixB, TPB_PIX, 0, stream>>>(x, C * L, ln_in_w, ln_in_b, x_ln, C * L, C, 1e-6f);
  k_conv1x1<8, 0, false><<<dim3(L / TPB, 256 / 8, B_SZ), TPB, 0, stream>>>(
      x_ln, C * L, inproj_w, inproj_b, xp, 128, 256);
  k_ln_cf<<<pixB, TPB_PIX, 0, stream>>>(xp, 2 * C * L, ln_m_w, ln_m_b, xlnm, C * L, C, 1e-6f);
  k_dwconv_silu<<<dim3(L / TPB, C, B_SZ), TPB, 0, stream>>>(xlnm, C * L, convm_w, convm_b, xm);
  k_dwconv_silu<<<dim3(L / TPB, C, B_SZ), TPB, 0, stream>>>(xp + (size_t)C * L, 2 * C * L,
                                                            convr_w, convr_b, xr);
  k_reverse<<<B_SZ * HALF * L / TPB, TPB, 0, stream>>>(xm, xb);
  k_unc<<<pixB, TPB_PIX, 0, stream>>>(xm, unc);
  k_sort<<<B_SZ, 1024, 0, stream>>>(unc, idx, inv);
  k_gather<<<elemB, TPB, 0, stream>>>(xm, idx, xs);

  // ---- selective scans ----
  auto run_scan = [&](const float* U, int ubs, int Cs, int R,
                      const float* Wx, const float* bx,
                      const float* Wdt, const float* bdt,
                      const float* Alog, const float* D, float* Y) {
    int O = R + 2 * N;
    k_conv1x1<4, 0, true><<<dim3(L / TPB, O / 4, B_SZ), TPB, 0, stream>>>(
        U, ubs, Wx, bx, xdbl, Cs, O);
    k_dt<<<dim3(L / TPB, Cs, B_SZ), TPB, 0, stream>>>(xdbl, O, R, Wdt, bdt, U, ubs,
                                                      dts, dtub, Cs);
    k_bc_t<<<B_SZ * N * L / TPB, TPB, 0, stream>>>(xdbl, O, R, BmT, CmT);
    int thr13 = B_SZ * Cs * N * NC;          // (b,c,n,chunk)
    k_scan1<<<thr13 / TPB, TPB, 0, stream>>>(dts, dtub, BmT, Alog, Ap, Hp, Cs);
    k_scan2<<<B_SZ * Cs * N * NC / TPB, TPB, 0, stream>>>(Ap, Hp, Hs);
    k_scan3<<<thr13 / TPB, TPB, 0, stream>>>(dts, dtub, BmT, CmT, Alog, Hs, U, ubs, D, Y, Cs);
  };

  run_scan(xm, C * L, HALF, 4, xpf_w, xpf_b, dtf_w, dtf_b, Alog_f, D_f, yf);
  run_scan(xb, HALF * L, HALF, 4, xpb_w, xpb_b, dtb_w, dtb_b, Alog_b, D_b, yb);
  run_scan(xs, C * L, C, 8, xpu_w, xpu_b, dtu_w, dtu_b, Alog_u, D_u, yus);

  k_ln_cat<<<pixB, TPB_PIX, 0, stream>>>(yf, yb, ln_cat_w, ln_cat_b, cat);
  k_unsort<<<elemB, TPB, 0, stream>>>(yus, inv, yu);
  k_conv1x1_cat2<8, 0><<<dim3(L / TPB, 128 / 8, B_SZ), TPB, 0, stream>>>(
      cat, C * L, yu, C * L, gate1_w, gate1_b, g1, 128);
  k_bn_stats<<<C, TPB, 0, stream>>>(g1, bn_g, bn_b, bnsc, bnsc + 128);
  k_bn_relu<<<elemB, TPB, 0, stream>>>(g1, bnsc, bnsc + 128);
  k_conv1x1<8, 1, false><<<dim3(L / TPB, 128 / 8, B_SZ), TPB, 0, stream>>>(
      g1, C * L, gate2_w, gate2_b, g, 128, 128);
  k_fuse<<<elemB, TPB, 0, stream>>>(g, yu, cat, fused);
  k_conv1x1_cat2<8, 0><<<dim3(L / TPB, 128 / 8, B_SZ), TPB, 0, stream>>>(
      fused, C * L, xr, C * L, outproj_w, outproj_b, outp, 128);
  k_ln_cf<<<pixB, TPB_PIX, 0, stream>>>(outp, C * L, outln_w, outln_b, (float*)d_out,
                                        C * L, C, 1e-6f);
}

// Round 3
// 469.197 us; speedup vs baseline: 3.9275x; 1.3167x over previous
//
#include <hip/hip_runtime.h>
#include <cstdint>
#include <cstddef>

#define TPB 256
#define TPB_PIX 64

namespace {

constexpr int B_SZ = 2;
constexpr int C    = 128;
constexpr int HALF = 64;
constexpr int L    = 4096;   // 64*64
constexpr int N    = 16;
constexpr int HH   = 64;
constexpr int WW   = 64;
constexpr int NC   = 64;     // number of chunks
constexpr int CS   = 64;     // chunk size (NC*CS == L)

__device__ __forceinline__ float softplusf(float x) {
  return fmaxf(x, 0.f) + log1pf(expf(-fabsf(x)));
}
__device__ __forceinline__ float sigm(float x) { return 1.f / (1.f + expf(-x)); }

// ---------- channel-first LayerNorm: 4 waves per 64-pixel tile ----------
// wave wv sums channels [wv*Cn/4, (wv+1)*Cn/4); LDS cross-wave reduce.
__global__ void k_ln_cf(const float* __restrict__ X, int bsX,
                        const float* __restrict__ w, const float* __restrict__ bchan,
                        float* __restrict__ Y, int bsY, int Cn, float eps) {
  const int lp = threadIdx.x & 63;
  const int wv = threadIdx.x >> 6;
  const int p  = blockIdx.x * 64 + lp;     // [0, B*L)
  const int b = p / L, l = p % L;
  const int Cq = Cn >> 2;
  const float* Xp = X + (size_t)b * bsX + l;
  float s = 0.f, s2 = 0.f;
#pragma unroll 8
  for (int i = 0; i < Cq; ++i) {
    float v = Xp[(size_t)(wv * Cq + i) * L];
    s += v; s2 += v * v;
  }
  __shared__ float r1[4][64], r2[4][64];
  r1[wv][lp] = s; r2[wv][lp] = s2;
  __syncthreads();
  float st  = r1[0][lp] + r1[1][lp] + r1[2][lp] + r1[3][lp];
  float s2t = r2[0][lp] + r2[1][lp] + r2[2][lp] + r2[3][lp];
  float mean = st / Cn;
  float var  = s2t / Cn - mean * mean;
  float rinv = rsqrtf(var + eps);
  float* Yp = Y + (size_t)b * bsY + l;
#pragma unroll 8
  for (int i = 0; i < Cq; ++i) {
    int c = wv * Cq + i;
    float v = Xp[(size_t)c * L];
    Yp[(size_t)c * L] = w[c] * (v - mean) * rinv + bchan[c];
  }
}

// ---------- LN over concat([yf, reverse_L(yb)]), same 4-wave structure ----------
__global__ void k_ln_cat(const float* __restrict__ yf, const float* __restrict__ ybr,
                         const float* __restrict__ w, const float* __restrict__ bchan,
                         float* __restrict__ Y) {
  const int lp = threadIdx.x & 63;
  const int wv = threadIdx.x >> 6;
  const int p  = blockIdx.x * 64 + lp;
  const int b = p / L, l = p % L;
  const float* f0 = yf  + (size_t)b * HALF * L + l;
  const float* b0 = ybr + (size_t)b * HALF * L + (L - 1 - l);
  const float* src = (wv < 2) ? f0 : b0;
  const int c0 = (wv & 1) * 32;      // channel within source
  const int cg0 = wv * 32;           // global channel
  float s = 0.f, s2 = 0.f;
#pragma unroll 8
  for (int i = 0; i < 32; ++i) {
    float v = src[(size_t)(c0 + i) * L];
    s += v; s2 += v * v;
  }
  __shared__ float r1[4][64], r2[4][64];
  r1[wv][lp] = s; r2[wv][lp] = s2;
  __syncthreads();
  float st  = r1[0][lp] + r1[1][lp] + r1[2][lp] + r1[3][lp];
  float s2t = r2[0][lp] + r2[1][lp] + r2[2][lp] + r2[3][lp];
  float mean = st / C;
  float var  = s2t / C - mean * mean;
  float rinv = rsqrtf(var + 1e-6f);
  float* Yp = Y + (size_t)b * C * L + l;
#pragma unroll 8
  for (int i = 0; i < 32; ++i) {
    float v = src[(size_t)(c0 + i) * L];
    int cg = cg0 + i;
    Yp[(size_t)cg * L] = w[cg] * (v - mean) * rinv + bchan[cg];
  }
}

// ---------- 1x1 conv: Y[b,o,l] = sum_i W[o,i]*X[b,i,l] + bias[o] ----------
template <int O_PB, int EPI, bool BLO>
__global__ void k_conv1x1(const float* __restrict__ X, int bsX,
                          const float* __restrict__ W, const float* __restrict__ bias,
                          float* __restrict__ Y, int I, int O) {
  __shared__ float Wl[O_PB * 256];
  const int o0 = blockIdx.y * O_PB;
  const int b  = blockIdx.z;
  for (int t = threadIdx.x; t < O_PB * I; t += TPB) {
    int i = t / O_PB, k = t % O_PB;
    Wl[t] = W[(size_t)(o0 + k) * I + i];
  }
  __syncthreads();
  const int l = blockIdx.x * TPB + threadIdx.x;
  const float* Xb = X + (size_t)b * bsX + l;
  float acc[O_PB];
#pragma unroll
  for (int k = 0; k < O_PB; ++k) acc[k] = bias[o0 + k];
#pragma unroll 4
  for (int i = 0; i < I; ++i) {
    float xv = Xb[(size_t)i * L];
#pragma unroll
    for (int k = 0; k < O_PB; ++k) acc[k] += Wl[i * O_PB + k] * xv;
  }
#pragma unroll
  for (int k = 0; k < O_PB; ++k) {
    float v = acc[k];
    if (EPI == 1) v = sigm(v);
    if (BLO) Y[((size_t)b * L + l) * O + o0 + k] = v;
    else     Y[((size_t)b * O + o0 + k) * L + l] = v;
  }
}

// ---------- 1x1 conv over concat of two (B,128,L) tensors ----------
template <int O_PB, int EPI>
__global__ void k_conv1x1_cat2(const float* __restrict__ X1, int bs1,
                               const float* __restrict__ X2, int bs2,
                               const float* __restrict__ W, const float* __restrict__ bias,
                               float* __restrict__ Y, int O) {
  __shared__ float Wl[O_PB * 256];
  const int o0 = blockIdx.y * O_PB;
  const int b  = blockIdx.z;
  for (int t = threadIdx.x; t < O_PB * 256; t += TPB) {
    int i = t / O_PB, k = t % O_PB;
    Wl[t] = W[(size_t)(o0 + k) * 256 + i];
  }
  __syncthreads();
  const int l = blockIdx.x * TPB + threadIdx.x;
  const float* Xb1 = X1 + (size_t)b * bs1 + l;
  const float* Xb2 = X2 + (size_t)b * bs2 + l;
  float acc[O_PB];
#pragma unroll
  for (int k = 0; k < O_PB; ++k) acc[k] = bias[o0 + k];
#pragma unroll 4
  for (int i = 0; i < 128; ++i) {
    float xv = Xb1[(size_t)i * L];
#pragma unroll
    for (int k = 0; k < O_PB; ++k) acc[k] += Wl[i * O_PB + k] * xv;
  }
#pragma unroll 4
  for (int i = 0; i < 128; ++i) {
    float xv = Xb2[(size_t)i * L];
#pragma unroll
    for (int k = 0; k < O_PB; ++k) acc[k] += Wl[(128 + i) * O_PB + k] * xv;
  }
#pragma unroll
  for (int k = 0; k < O_PB; ++k) {
    float v = acc[k];
    if (EPI == 1) v = sigm(v);
    Y[((size_t)b * O + o0 + k) * L + l] = v;
  }
}

// ---------- depthwise 3x3 SAME + bias + SiLU ----------
__global__ void k_dwconv_silu(const float* __restrict__ X, int bsX,
                              const float* __restrict__ W9, const float* __restrict__ bias,
                              float* __restrict__ Y) {
  int c = blockIdx.y, b = blockIdx.z;
  int l = blockIdx.x * TPB + threadIdx.x;
  int h = l / WW, w = l % WW;
  const float* Xc = X + (size_t)b * bsX + (size_t)c * L;
  float acc = bias[c];
#pragma unroll
  for (int kh = 0; kh < 3; ++kh) {
    int hh = h + kh - 1;
    if (hh < 0 || hh >= HH) continue;
#pragma unroll
    for (int kw = 0; kw < 3; ++kw) {
      int ww2 = w + kw - 1;
      if (ww2 < 0 || ww2 >= WW) continue;
      acc += Xc[hh * WW + ww2] * W9[c * 9 + kh * 3 + kw];
    }
  }
  Y[((size_t)b * C + c) * L + l] = acc * sigm(acc);
}

// ---------- reverse second half channels along L ----------
__global__ void k_reverse(const float* __restrict__ xm, float* __restrict__ xb) {
  int t = blockIdx.x * TPB + threadIdx.x;   // B*HALF*L
  int l = t % L, c = (t / L) % HALF, b = t / (HALF * L);
  xb[t] = xm[((size_t)b * C + HALF + c) * L + (L - 1 - l)];
}

// ---------- uncertainty per pixel: 4-wave structure ----------
__global__ void k_unc(const float* __restrict__ xm, float* __restrict__ unc) {
  const int lp = threadIdx.x & 63;
  const int wv = threadIdx.x >> 6;
  const int p  = blockIdx.x * 64 + lp;
  const int b = p / L, l = p % L;
  const float* Xp = xm + (size_t)b * C * L + l;
  float s = 0.f;
#pragma unroll 8
  for (int i = 0; i < 32; ++i) s += Xp[(size_t)(wv * 32 + i) * L];
  __shared__ float r1[4][64];
  r1[wv][lp] = s;
  __syncthreads();
  if (wv == 0) {
    float st = r1[0][lp] + r1[1][lp] + r1[2][lp] + r1[3][lp];
    float sg = sigm(st / C);
    unc[p] = -(sg * logf(sg + 1e-6f));
  }
}

// ---------- stable argsort(-unc): register/shfl bitonic ----------
// 1024 threads; thread owns elements [4t, 4t+3]. Stages with j<=128 run in
// registers (j<=2 in-thread, j=4..128 via __shfl_xor, partner lane = lane^(j/4)).
// Only j>=256 stages touch LDS. k=2..256 prefix: zero barriers.
__global__ void k_sort(const float* __restrict__ unc, int* __restrict__ idx,
                       int* __restrict__ inv) {
  __shared__ unsigned long long S[L];
  const int b = blockIdx.x;
  const int tid = threadIdx.x;          // 0..1023
  const int e0 = tid * 4;

  unsigned long long v[4];
  // build keys straight into registers (coalesced float4 read)
  {
    float4 u4 = ((const float4*)(unc + b * L))[tid];
    float uv[4] = {u4.x, u4.y, u4.z, u4.w};
#pragma unroll
    for (int r = 0; r < 4; ++r) {
      unsigned u = __float_as_uint(uv[r]);
      u = (u & 0x80000000u) ? ~u : (u | 0x80000000u);  // monotone ascending
      v[r] = ((unsigned long long)(~u) << 32) | (unsigned)(e0 + r);
    }
  }

  // ---- mega register pass: k = 2 .. 256 (no barriers) ----
  for (int k = 2; k <= 256; k <<= 1) {
    for (int j = k >> 1; j > 0; j >>= 1) {
      if (j >= 4) {
        int m = j >> 2;
#pragma unroll
        for (int r = 0; r < 4; ++r) {
          unsigned long long p = __shfl_xor(v[r], m);
          int e = e0 + r;
          bool keepmin = (((e & k) == 0) == ((e & j) == 0));
          v[r] = keepmin ? (v[r] < p ? v[r] : p) : (v[r] > p ? v[r] : p);
        }
      } else {
#pragma unroll
        for (int r = 0; r < 4; ++r) {
          int rp = r ^ j;
          if (rp > r) {
            int e = e0 + r;
            bool up = ((e & k) == 0);
            unsigned long long a = v[r], bb = v[rp];
            if ((a > bb) == up) { v[r] = bb; v[rp] = a; }
          }
        }
      }
    }
  }
#pragma unroll
  for (int r = 0; r < 4; ++r) S[e0 + r] = v[r];
  __syncthreads();

  // ---- k = 512 .. 4096: LDS stages for j>=256, register pass for j<=128 ----
  for (int k = 512; k <= L; k <<= 1) {
    for (int j = k >> 1; j >= 256; j >>= 1) {
      for (int q = tid; q < L / 2; q += 1024) {
        int i = ((q & ~(j - 1)) << 1) | (q & (j - 1));
        int ixj = i | j;
        unsigned long long a = S[i], bb = S[ixj];
        bool up = ((i & k) == 0);
        if ((a > bb) == up) { S[i] = bb; S[ixj] = a; }
      }
      __syncthreads();
    }
#pragma unroll
    for (int r = 0; r < 4; ++r) v[r] = S[e0 + r];
    const bool up = ((e0 & k) == 0);   // uniform over the 4 owned elements (k>=512)
    for (int j = 128; j >= 4; j >>= 1) {
      int m = j >> 2;
#pragma unroll
      for (int r = 0; r < 4; ++r) {
        unsigned long long p = __shfl_xor(v[r], m);
        int e = e0 + r;
        bool keepmin = (up == ((e & j) == 0));
        v[r] = keepmin ? (v[r] < p ? v[r] : p) : (v[r] > p ? v[r] : p);
      }
    }
#pragma unroll
    for (int j = 2; j > 0; j >>= 1) {
#pragma unroll
      for (int r = 0; r < 4; ++r) {
        int rp = r ^ j;
        if (rp > r) {
          unsigned long long a = v[r], bb = v[rp];
          if ((a > bb) == up) { v[r] = bb; v[rp] = a; }
        }
      }
    }
#pragma unroll
    for (int r = 0; r < 4; ++r) S[e0 + r] = v[r];
    __syncthreads();
  }

  for (int i = tid; i < L; i += 1024) {
    int orig = (int)(S[i] & 0xffffffffu);
    idx[b * L + i] = orig;
    inv[b * L + orig] = i;
  }
}

// ---------- gather / unsort ----------
__global__ void k_gather(const float* __restrict__ xm, const int* __restrict__ idx,
                         float* __restrict__ xs) {
  int t = blockIdx.x * TPB + threadIdx.x;   // B*C*L
  int k = t % L, c = (t / L) % C, b = t / (C * L);
  xs[t] = xm[((size_t)b * C + c) * L + idx[b * L + k]];
}

__global__ void k_unsort(const float* __restrict__ yus, const int* __restrict__ inv,
                         float* __restrict__ yu) {
  int t = blockIdx.x * TPB + threadIdx.x;   // B*C*L
  int l = t % L, c = (t / L) % C, b = t / (C * L);
  yu[t] = yus[((size_t)b * C + c) * L + inv[b * L + l]];
}

// ---------- dt: scrambled reshape + double bias + softplus; dtu = dts*u ----------
__global__ void k_dt(const float* __restrict__ xdbl, int O, int R,
                     const float* __restrict__ Wdt, const float* __restrict__ bdt,
                     const float* __restrict__ U, int ubs,
                     float* __restrict__ dts, float* __restrict__ dtu, int Cs) {
  int c2 = blockIdx.y, b = blockIdx.z;
  int l2 = blockIdx.x * TPB + threadIdx.x;
  int f = c2 * L + l2;
  int lsrc = f / Cs, csrc = f % Cs;
  const float* xr = xdbl + ((size_t)b * L + lsrc) * O;
  float acc = bdt[csrc] + bdt[c2];
  for (int r = 0; r < R; ++r) acc += Wdt[csrc * R + r] * xr[r];
  float d = softplusf(acc);
  size_t o = ((size_t)b * Cs + c2) * L + l2;
  dts[o] = d;
  dtu[o] = d * U[(size_t)b * ubs + (size_t)c2 * L + l2];
}

// ---------- Bm/Cm scrambled reshape -> TRANSPOSED (B, L, N) layout ----------
__global__ void k_bc_t(const float* __restrict__ xdbl, int O, int R,
                       float* __restrict__ BmT, float* __restrict__ CmT) {
  int t = blockIdx.x * TPB + threadIdx.x;   // B*L*N
  int n = t & 15, l = (t >> 4) & (L - 1), b = t >> 16;
  int f = n * L + l;
  int lb = f >> 4, cb = f & 15;
  const float* xr = xdbl + ((size_t)b * L + lb) * O + R + cb;
  BmT[t] = xr[0];
  CmT[t] = xr[N];
}

// ---------- scan phase 1: thread = (b, c, n, chunk); n in low 4 lane bits ----------
__global__ void k_scan1(const float* __restrict__ dts, const float* __restrict__ dtu,
                        const float* __restrict__ BmT, const float* __restrict__ Alog,
                        float* __restrict__ Ap, float* __restrict__ Hp, int Cs) {
  int t = blockIdx.x * TPB + threadIdx.x;
  int n = t & 15;
  int chunk = (t >> 4) & (NC - 1);
  int rc = t >> 10;                 // b*Cs + c
  int c = rc % Cs, b = rc / Cs;
  float a = -expf(Alog[c * N + n]);
  float ap = 1.f, h = 0.f;
  size_t rowoff = (size_t)rc * L + chunk * CS;
  const float4* dp4 = (const float4*)(dts + rowoff);
  const float4* up4 = (const float4*)(dtu + rowoff);
  const float* bp = BmT + (((size_t)b * L + chunk * CS) << 4) + n;
#pragma unroll
  for (int j = 0; j < CS / 4; ++j) {
    float4 d4 = dp4[j], du4 = up4[j];
    float dv[4] = {d4.x, d4.y, d4.z, d4.w};
    float uv[4] = {du4.x, du4.y, du4.z, du4.w};
#pragma unroll
    for (int jj = 0; jj < 4; ++jj) {
      int s = 4 * j + jj;
      float bn = bp[(size_t)s << 4];
      float dA = expf(dv[jj] * a);
      ap *= dA;
      h = h * dA + uv[jj] * bn;
    }
  }
  size_t base = ((size_t)rc * N + n) * NC + chunk;
  Ap[base] = ap;
  Hp[base] = h;
}

// ---------- scan phase 2: wave-parallel log-scan over chunks ----------
__global__ void k_scan2(const float* __restrict__ Ap, const float* __restrict__ Hp,
                        float* __restrict__ Hs) {
  int t = blockIdx.x * TPB + threadIdx.x;
  int k = t & 63;
  size_t row = (size_t)(t >> 6) * NC;
  float A = Ap[row + k];
  float B = Hp[row + k];
#pragma unroll
  for (int j = 1; j < NC; j <<= 1) {
    float pa = __shfl_up(A, j);
    float pb = __shfl_up(B, j);
    if (k >= j) { B = pb * A + B; A = pa * A; }
  }
  float hprev = __shfl_up(B, 1);
  Hs[row + k] = (k == 0) ? 0.f : hprev;
}

// ---------- scan phase 3: replay with h_start; y = sum_n h*C + u*D ----------
__global__ void k_scan3(const float* __restrict__ dts, const float* __restrict__ dtu,
                        const float* __restrict__ BmT, const float* __restrict__ CmT,
                        const float* __restrict__ Alog, const float* __restrict__ Hs,
                        const float* __restrict__ U, int ubs, const float* __restrict__ D,
                        float* __restrict__ Y, int Cs) {
  int t = blockIdx.x * TPB + threadIdx.x;
  int n = t & 15;
  int chunk = (t >> 4) & (NC - 1);
  int rc = t >> 10;
  int c = rc % Cs, b = rc / Cs;
  float a = -expf(Alog[c * N + n]);
  float h = Hs[((size_t)rc * N + n) * NC + chunk];
  float Dc = D[c];
  size_t rowoff = (size_t)rc * L + chunk * CS;
  const float4* dp4 = (const float4*)(dts + rowoff);
  const float4* up4 = (const float4*)(dtu + rowoff);
  const float4* uu4 = (const float4*)(U + (size_t)b * ubs + (size_t)c * L + chunk * CS);
  const float* bp = BmT + (((size_t)b * L + chunk * CS) << 4) + n;
  const float* cp = CmT + (((size_t)b * L + chunk * CS) << 4) + n;
  float ybuf[4];
#pragma unroll
  for (int j = 0; j < CS / 4; ++j) {
    float4 d4 = dp4[j], du4 = up4[j], u4 = uu4[j];
    float dv[4] = {d4.x, d4.y, d4.z, d4.w};
    float uv[4] = {du4.x, du4.y, du4.z, du4.w};
    float xv[4] = {u4.x, u4.y, u4.z, u4.w};
#pragma unroll
    for (int jj = 0; jj < 4; ++jj) {
      int s = 4 * j + jj;
      float bn = bp[(size_t)s << 4];
      float cn = cp[(size_t)s << 4];
      float dA = expf(dv[jj] * a);
      h = h * dA + uv[jj] * bn;
      float p = h * cn;
      p += __shfl_xor(p, 1);
      p += __shfl_xor(p, 2);
      p += __shfl_xor(p, 4);
      p += __shfl_xor(p, 8);
      float yv = p + xv[jj] * Dc;
      if ((s & 15) == n) ybuf[s >> 4] = yv;
    }
  }
  float* yp = Y + rowoff;
#pragma unroll
  for (int q = 0; q < 4; ++q) yp[16 * q + n] = ybuf[q];
}

// ---------- BN train-mode stats -> per-channel scale/shift ----------
__global__ void k_bn_stats(const float* __restrict__ X, const float* __restrict__ g,
                           const float* __restrict__ bb, float* __restrict__ scale,
                           float* __restrict__ shift) {
  int c = blockIdx.x;
  float s = 0.f, s2 = 0.f;
  for (int t = threadIdx.x; t < B_SZ * L; t += TPB) {
    int b = t / L, l = t % L;
    float v = X[((size_t)b * C + c) * L + l];
    s += v; s2 += v * v;
  }
  __shared__ float r1[TPB], r2[TPB];
  r1[threadIdx.x] = s; r2[threadIdx.x] = s2;
  __syncthreads();
  for (int off = TPB / 2; off > 0; off >>= 1) {
    if (threadIdx.x < off) {
      r1[threadIdx.x] += r1[threadIdx.x + off];
      r2[threadIdx.x] += r2[threadIdx.x + off];
    }
    __syncthreads();
  }
  if (threadIdx.x == 0) {
    float mean = r1[0] / (B_SZ * L);
    float var  = r2[0] / (B_SZ * L) - mean * mean;
    float sc = g[c] * rsqrtf(var + 1e-5f);
    scale[c] = sc;
    shift[c] = bb[c] - mean * sc;
  }
}

__global__ void k_bn_relu(float* __restrict__ X, const float* __restrict__ scale,
                          const float* __restrict__ shift) {
  int t = blockIdx.x * TPB + threadIdx.x;   // B*C*L
  int c = (t / L) % C;
  float v = scale[c] * X[t] + shift[c];
  X[t] = fmaxf(v, 0.f);
}

__global__ void k_fuse(const float* __restrict__ g, const float* __restrict__ yu,
                       const float* __restrict__ cat, float* __restrict__ out) {
  int t = blockIdx.x * TPB + threadIdx.x;
  float gv = g[t];
  out[t] = gv * yu[t] + (1.f - gv) * cat[t];
}

} // namespace

extern "C" void kernel_launch(void* const* d_in, const int* in_sizes, int n_in,
                              void* d_out, int out_size, void* d_ws, size_t ws_size,
                              hipStream_t stream) {
  const float* x         = (const float*)d_in[0];
  const float* ln_in_w   = (const float*)d_in[1];
  const float* ln_in_b   = (const float*)d_in[2];
  const float* inproj_w  = (const float*)d_in[3];
  const float* inproj_b  = (const float*)d_in[4];
  const float* ln_m_w    = (const float*)d_in[5];
  const float* ln_m_b    = (const float*)d_in[6];
  const float* convm_w   = (const float*)d_in[7];
  const float* convm_b   = (const float*)d_in[8];
  const float* convr_w   = (const float*)d_in[9];
  const float* convr_b   = (const float*)d_in[10];
  const float* ln_cat_w  = (const float*)d_in[11];
  const float* ln_cat_b  = (const float*)d_in[12];
  const float* xpf_w     = (const float*)d_in[13];
  const float* xpf_b     = (const float*)d_in[14];
  const float* dtf_w     = (const float*)d_in[15];
  const float* dtf_b     = (const float*)d_in[16];
  const float* Alog_f    = (const float*)d_in[17];
  const float* D_f       = (const float*)d_in[18];
  const float* xpb_w     = (const float*)d_in[19];
  const float* xpb_b     = (const float*)d_in[20];
  const float* dtb_w     = (const float*)d_in[21];
  const float* dtb_b     = (const float*)d_in[22];
  const float* Alog_b    = (const float*)d_in[23];
  const float* D_b       = (const float*)d_in[24];
  const float* xpu_w     = (const float*)d_in[25];
  const float* xpu_b     = (const float*)d_in[26];
  const float* dtu_w     = (const float*)d_in[27];
  const float* dtu_b     = (const float*)d_in[28];
  const float* Alog_u    = (const float*)d_in[29];
  const float* D_u       = (const float*)d_in[30];
  const float* gate1_w   = (const float*)d_in[31];
  const float* gate1_b   = (const float*)d_in[32];
  const float* bn_g      = (const float*)d_in[33];
  const float* bn_b      = (const float*)d_in[34];
  const float* gate2_w   = (const float*)d_in[35];
  const float* gate2_b   = (const float*)d_in[36];
  const float* outproj_w = (const float*)d_in[37];
  const float* outproj_b = (const float*)d_in[38];
  const float* outln_w   = (const float*)d_in[39];
  const float* outln_b   = (const float*)d_in[40];

  float* ws = (float*)d_ws;
  size_t off = 0;
  auto alloc = [&](size_t n) { float* p = ws + off; off += n; return p; };

  float* x_ln  = alloc((size_t)B_SZ * C * L);
  float* xp    = alloc((size_t)B_SZ * 2 * C * L);
  float* xlnm  = alloc((size_t)B_SZ * C * L);
  float* xm    = alloc((size_t)B_SZ * C * L);
  float* xr    = alloc((size_t)B_SZ * C * L);
  float* xb    = alloc((size_t)B_SZ * HALF * L);
  float* unc   = alloc((size_t)B_SZ * L);
  int*   idx   = (int*)alloc((size_t)B_SZ * L);
  int*   inv   = (int*)alloc((size_t)B_SZ * L);
  float* xs    = alloc((size_t)B_SZ * C * L);
  float* xdbl  = alloc((size_t)B_SZ * L * 40);
  float* dts   = alloc((size_t)B_SZ * C * L);
  float* dtub  = alloc((size_t)B_SZ * C * L);
  float* BmT   = alloc((size_t)B_SZ * N * L);
  float* CmT   = alloc((size_t)B_SZ * N * L);
  float* Ap    = alloc((size_t)B_SZ * C * N * NC);
  float* Hp    = alloc((size_t)B_SZ * C * N * NC);
  float* Hs    = alloc((size_t)B_SZ * C * N * NC);
  float* yf    = alloc((size_t)B_SZ * HALF * L);
  float* yb    = alloc((size_t)B_SZ * HALF * L);
  float* yus   = alloc((size_t)B_SZ * C * L);
  float* yu    = alloc((size_t)B_SZ * C * L);
  float* cat   = alloc((size_t)B_SZ * C * L);
  float* g1    = alloc((size_t)B_SZ * C * L);
  float* bnsc  = alloc(256);
  float* g     = alloc((size_t)B_SZ * C * L);
  float* fused = alloc((size_t)B_SZ * C * L);
  float* outp  = alloc((size_t)B_SZ * C * L);
  (void)ws_size; (void)in_sizes; (void)n_in; (void)out_size;

  const int pixB = B_SZ * L / 64;          // 128 blocks of 256 threads (4 waves/64 px)
  const int elemB = B_SZ * C * L / TPB;    // 4096

  k_ln_cf<<<pixB, TPB, 0, stream>>>(x, C * L, ln_in_w, ln_in_b, x_ln, C * L, C, 1e-6f);
  k_conv1x1<8, 0, false><<<dim3(L / TPB, 256 / 8, B_SZ), TPB, 0, stream>>>(
      x_ln, C * L, inproj_w, inproj_b, xp, 128, 256);
  k_ln_cf<<<pixB, TPB, 0, stream>>>(xp, 2 * C * L, ln_m_w, ln_m_b, xlnm, C * L, C, 1e-6f);
  k_dwconv_silu<<<dim3(L / TPB, C, B_SZ), TPB, 0, stream>>>(xlnm, C * L, convm_w, convm_b, xm);
  k_dwconv_silu<<<dim3(L / TPB, C, B_SZ), TPB, 0, stream>>>(xp + (size_t)C * L, 2 * C * L,
                                                            convr_w, convr_b, xr);
  k_reverse<<<B_SZ * HALF * L / TPB, TPB, 0, stream>>>(xm, xb);
  k_unc<<<pixB, TPB, 0, stream>>>(xm, unc);
  k_sort<<<B_SZ, 1024, 0, stream>>>(unc, idx, inv);
  k_gather<<<elemB, TPB, 0, stream>>>(xm, idx, xs);

  // ---- selective scans ----
  auto run_scan = [&](const float* U, int ubs, int Cs, int R,
                      const float* Wx, const float* bx,
                      const float* Wdt, const float* bdt,
                      const float* Alog, const float* D, float* Y) {
    int O = R + 2 * N;
    k_conv1x1<4, 0, true><<<dim3(L / TPB, O / 4, B_SZ), TPB, 0, stream>>>(
        U, ubs, Wx, bx, xdbl, Cs, O);
    k_dt<<<dim3(L / TPB, Cs, B_SZ), TPB, 0, stream>>>(xdbl, O, R, Wdt, bdt, U, ubs,
                                                      dts, dtub, Cs);
    k_bc_t<<<B_SZ * N * L / TPB, TPB, 0, stream>>>(xdbl, O, R, BmT, CmT);
    int thr13 = B_SZ * Cs * N * NC;          // (b,c,n,chunk)
    k_scan1<<<thr13 / TPB, TPB, 0, stream>>>(dts, dtub, BmT, Alog, Ap, Hp, Cs);
    k_scan2<<<B_SZ * Cs * N * NC / TPB, TPB, 0, stream>>>(Ap, Hp, Hs);
    k_scan3<<<thr13 / TPB, TPB, 0, stream>>>(dts, dtub, BmT, CmT, Alog, Hs, U, ubs, D, Y, Cs);
  };

  run_scan(xm, C * L, HALF, 4, xpf_w, xpf_b, dtf_w, dtf_b, Alog_f, D_f, yf);
  run_scan(xb, HALF * L, HALF, 4, xpb_w, xpb_b, dtb_w, dtb_b, Alog_b, D_b, yb);
  run_scan(xs, C * L, C, 8, xpu_w, xpu_b, dtu_w, dtu_b, Alog_u, D_u, yus);

  k_ln_cat<<<pixB, TPB, 0, stream>>>(yf, yb, ln_cat_w, ln_cat_b, cat);
  k_unsort<<<elemB, TPB, 0, stream>>>(yus, inv, yu);
  k_conv1x1_cat2<8, 0><<<dim3(L / TPB, 128 / 8, B_SZ), TPB, 0, stream>>>(
      cat, C * L, yu, C * L, gate1_w, gate1_b, g1, 128);
  k_bn_stats<<<C, TPB, 0, stream>>>(g1, bn_g, bn_b, bnsc, bnsc + 128);
  k_bn_relu<<<elemB, TPB, 0, stream>>>(g1, bnsc, bnsc + 128);
  k_conv1x1<8, 1, false><<<dim3(L / TPB, 128 / 8, B_SZ), TPB, 0, stream>>>(
      g1, C * L, gate2_w, gate2_b, g, 128, 128);
  k_fuse<<<elemB, TPB, 0, stream>>>(g, yu, cat, fused);
  k_conv1x1_cat2<8, 0><<<dim3(L / TPB, 128 / 8, B_SZ), TPB, 0, stream>>>(
      fused, C * L, xr, C * L, outproj_w, outproj_b, outp, 128);
  k_ln_cf<<<pixB, TPB, 0, stream>>>(outp, C * L, outln_w, outln_b, (float*)d_out,
                                    C * L, C, 1e-6f);
}